// Round 9
// baseline (234.869 us; speedup 1.0000x reference)
//
#include <hip/hip_runtime.h>
#include <hip/hip_fp16.h>
#include <hip/hip_cooperative_groups.h>

namespace cg = cooperative_groups;

#define H 64
#define NA 65536
#define NB 131072
#define NM 16384
#define NC 2048
#define E_AC 65536
#define E_BC 131072
#define E_MC 16384
#define NE_TOT (E_AC + E_BC + E_MC)

#define CAPA 160
#define CAPB 224
#define CAPM 96
#define SLOTB (NC * CAPA)
#define SLOTM (SLOTB + NC * CAPB)
#define SLOT_TOT (SLOTM + NC * CAPM)

// phase-B virtual unit layout
#define NU_GA 1024
#define NU_GM 256
#define NU_CP 384
#define NU_AP 104
#define NU_B (NU_GA + NU_GM + NU_CP + NU_AP)

typedef __attribute__((ext_vector_type(8))) short bf16x8;
typedef __attribute__((ext_vector_type(4))) float f32x4;

__device__ __forceinline__ float sigmoidf_(float x) { return 1.0f / (1.0f + __expf(-x)); }
__device__ __forceinline__ float softplusf_(float x) {
    return fmaxf(x, 0.0f) + __logf(1.0f + __expf(-fabsf(x)));
}
__device__ __forceinline__ short bf16_of(float f) {
    union { float f; unsigned u; } v; v.f = f;
    unsigned r = (v.u + 0x7fff + ((v.u >> 16) & 1)) >> 16;  // RNE
    return (short)r;
}

// G build tile: one wave = 16 rows x 128 cols. B-fragments reloaded per K-step (VGPR diet).
template<int K, int S, bool VEC>
__device__ __forceinline__ void gmfma_body(
    int blk, const float* __restrict__ x, const short* __restrict__ wp,
    const float* __restrict__ bias, __half2* __restrict__ g)
{
    int l = threadIdx.x & 63;
    int wv = threadIdx.x >> 6;
    int r0 = (blk * 4 + wv) * 16;
    int lrow = l & 15, q = l >> 4;

    float bF[4], bS[4];
    #pragma unroll
    for (int t = 0; t < 4; ++t) {
        bF[t] = bias[t * 16 + lrow];
        bS[t] = bias[64 + t * 16 + lrow];
    }

    f32x4 acc[8];
    #pragma unroll
    for (int t = 0; t < 8; ++t) acc[t] = (f32x4){0.f, 0.f, 0.f, 0.f};

    const float* xr = x + (size_t)(r0 + lrow) * K;
    #pragma unroll
    for (int s = 0; s < S; ++s) {
        int kb = s * 32 + q * 8;
        bf16x8 afrag;
        if (VEC && kb + 8 <= K) {                 // row stride K*4 is 16B-aligned (K=92)
            float4 v0 = *(const float4*)(xr + kb);
            float4 v1 = *(const float4*)(xr + kb + 4);
            afrag[0] = bf16_of(v0.x); afrag[1] = bf16_of(v0.y);
            afrag[2] = bf16_of(v0.z); afrag[3] = bf16_of(v0.w);
            afrag[4] = bf16_of(v1.x); afrag[5] = bf16_of(v1.y);
            afrag[6] = bf16_of(v1.z); afrag[7] = bf16_of(v1.w);
        } else {
            #pragma unroll
            for (int e = 0; e < 8; ++e) {
                float xv = 0.0f;
                if (kb + e < K) xv = xr[kb + e];
                afrag[e] = bf16_of(xv);
            }
        }
        #pragma unroll
        for (int t = 0; t < 8; ++t) {
            bf16x8 bt = *(const bf16x8*)(wp + (size_t)((t * S + s) * 64 + l) * 8);
            acc[t] = __builtin_amdgcn_mfma_f32_16x16x32_bf16(afrag, bt, acc[t], 0, 0, 0);
        }
    }

    #pragma unroll
    for (int t = 0; t < 4; ++t)
        #pragma unroll
        for (int r = 0; r < 4; ++r) {
            float fv = acc[t][r] + bF[t];
            float sv = acc[t + 4][r] + bS[t];
            g[(size_t)(r0 + q * 4 + r) * H + t * 16 + lrow] = __floats2half2_rn(fv, sv);
        }
}

__global__ __launch_bounds__(256, 4) void fused_kernel(
    const float* __restrict__ xa, const float* __restrict__ xb,
    const float* __restrict__ xm, const float* __restrict__ xc,
    const float* __restrict__ Wa, const float* __restrict__ ba,
    const float* __restrict__ Wb, const float* __restrict__ bb_,
    const float* __restrict__ Wm, const float* __restrict__ bm,
    const float* __restrict__ Wf, const float* __restrict__ bf,
    const float* __restrict__ Ws, const float* __restrict__ bs,
    const float* __restrict__ Wp, const float* __restrict__ bp,
    const float* __restrict__ Wo, const float* __restrict__ bo,
    const int* __restrict__ ea, const int* __restrict__ eb, const int* __restrict__ em,
    float* __restrict__ Cf, float* __restrict__ Cs,
    int* __restrict__ cnt, int* __restrict__ slots,
    short* __restrict__ wpA, short* __restrict__ wpM,
    float* __restrict__ biasA, float* __restrict__ biasM,
    __half2* __restrict__ WcB,
    __half2* __restrict__ gA, __half2* __restrict__ gM,
    float* __restrict__ out)
{
    cg::grid_group grid = cg::this_grid();
    __shared__ float smem[8192];                 // 32 KB, aliased across phases
    int tid = threadIdx.x;

    // ================= Phase A: cnt zero + weight packs =================
    for (int i = blockIdx.x * 256 + tid; i < 3 * NC; i += gridDim.x * 256) cnt[i] = 0;

    for (int u = blockIdx.x; u < 84; u += gridDim.x) {
        if (u < 48) {                             // atom MFMA-pack: 96x128
            int idx = u * 256 + tid;
            int k = idx >> 7, col = idx & 127, c = col & 63;
            const float* WB = ((col < 64) ? Wf : Ws) + (size_t)6 * 2 * H * H + (size_t)H * H;
            float v = 0.0f;
            if (k < 92) {
                const float* a = Wa + (size_t)k * H;
                for (int j = 0; j < H; ++j) v = fmaf(a[j], WB[j * H + c], v);
            }
            int t = col >> 4, lo = col & 15, sm = k >> 5, q = (k >> 3) & 3, e = k & 7;
            wpA[(size_t)(((t * 3 + sm) * 64) + q * 16 + lo) * 8 + e] = bf16_of(v);
        } else if (u < 80) {                      // motif MFMA-pack: 64x128
            int idx = (u - 48) * 256 + tid;
            int k = idx >> 7, col = idx & 127, c = col & 63;
            const float* WB = ((col < 64) ? Wf : Ws) + (size_t)8 * 2 * H * H + (size_t)H * H;
            float v = 0.0f;
            if (k < 35) {
                const float* a = Wm + (size_t)k * H;
                for (int j = 0; j < H; ++j) v = fmaf(a[j], WB[j * H + c], v);
            }
            int t = col >> 4, lo = col & 15, sm = k >> 5, q = (k >> 3) & 3, e = k & 7;
            wpM[(size_t)(((t * 2 + sm) * 64) + q * 16 + lo) * 8 + e] = bf16_of(v);
        } else if (u == 80) {
            if (tid < 128) {
                int col = tid, c = col & 63;
                const float* WB = ((col < 64) ? Wf : Ws) + (size_t)6 * 2 * H * H + (size_t)H * H;
                float v = 0.0f;
                for (int j = 0; j < H; ++j) v = fmaf(ba[j], WB[j * H + c], v);
                biasA[col] = v;
            }
        } else if (u == 81) {
            if (tid < 128) {
                int col = tid, c = col & 63;
                const float* WB = ((col < 64) ? Wf : Ws) + (size_t)8 * 2 * H * H + (size_t)H * H;
                float v = 0.0f;
                for (int j = 0; j < H; ++j) v = fmaf(bm[j], WB[j * H + c], v);
                biasM[col] = v;
            }
        } else {                                  // bond composite weights: 8x64
            int idx = (u - 82) * 256 + tid;
            if (idx < 8 * 64) {
                int k = idx >> 6, col = idx & 63;
                const float* WfB = Wf + (size_t)7 * 2 * H * H + (size_t)H * H;
                const float* WsB = Ws + (size_t)7 * 2 * H * H + (size_t)H * H;
                const float* row = (k < 7) ? (Wb + (size_t)k * H) : bb_;
                float f = 0.0f, s = 0.0f;
                for (int j = 0; j < H; ++j) {
                    float rv = row[j];
                    f = fmaf(rv, WfB[j * H + col], f);
                    s = fmaf(rv, WsB[j * H + col], s);
                }
                WcB[k * 64 + col] = __floats2half2_rn(f, s);
            }
        }
    }
    grid.sync();

    // ================= Phase B: G build + cellpart + edge append =================
    for (int u = blockIdx.x; u < NU_B; u += gridDim.x) {
        if (u < NU_GA) {
            gmfma_body<92, 3, true>(u, xa, wpA, biasA, gA);
        } else if (u < NU_GA + NU_GM) {
            gmfma_body<35, 2, false>(u - NU_GA, xm, wpM, biasM, gM);
        } else if (u < NU_GA + NU_GM + NU_CP) {   // cellpart: Cf/Cs
            __syncthreads();                      // protect smem from previous unit
            int cu = u - NU_GA - NU_GM;           // 0..383
            int r = cu / 128, rowblk = cu % 128;
            const float* WfT = Wf + (size_t)(6 + r) * 2 * H * H;
            const float* WsT = Ws + (size_t)(6 + r) * 2 * H * H;
            for (int i = tid; i < H * H; i += 256) { smem[i] = WfT[i]; smem[4096 + i] = WsT[i]; }
            __syncthreads();
            int col = tid & 63, rgrp = tid >> 6;
            float bfv = bf[(6 + r) * H + col], bsv = bs[(6 + r) * H + col];
            #pragma unroll
            for (int rr = 0; rr < 4; ++rr) {
                int row = rowblk * 16 + rgrp * 4 + rr;
                const float* xr = xc + (size_t)row * H;
                float af = bfv, as = bsv;
                #pragma unroll
                for (int k = 0; k < H; ++k) {
                    float xv = xr[k];
                    af = fmaf(xv, smem[k * H + col], af);
                    as = fmaf(xv, smem[4096 + k * H + col], as);
                }
                Cf[((size_t)r * NC + row) * H + col] = af;
                Cs[((size_t)r * NC + row) * H + col] = as;
            }
        } else {                                  // edge append
            int t0 = (u - NU_GA - NU_GM - NU_CP) * 256 + tid;   // 0..26623
            #pragma unroll
            for (int u2 = 0; u2 < 8; ++u2) {
                int i = t0 + u2 * 26624;
                int r, d, s;
                if (i < E_AC)             { r = 0; s = ea[i];                 d = ea[E_AC + i]; }
                else if (i < E_AC + E_BC) { int k = i - E_AC; r = 1; s = eb[k]; d = eb[E_BC + k]; }
                else                      { int k = i - E_AC - E_BC; r = 2; s = em[k]; d = em[E_MC + k]; }
                int pos = atomicAdd(&cnt[r * NC + d], 1);
                int base, cap;
                if (r == 0)      { base = d * CAPA;         cap = CAPA; }
                else if (r == 1) { base = SLOTB + d * CAPB; cap = CAPB; }
                else             { base = SLOTM + d * CAPM; cap = CAPM; }
                if (pos < cap) slots[base + pos] = s;
            }
        }
    }
    grid.sync();

    // ================= Phase C: per-cell accumulate + head =================
    float* red = smem;            // [4][64]
    float* vL  = smem + 256;      // [64]
    int lane = tid & 63, wv = tid >> 6;
    for (int d = blockIdx.x; d < NC; d += gridDim.x) {
        float acc = 0.0f;
        // atom: gather gA
        {
            int n = min(cnt[d], CAPA);
            float cfv = Cf[(size_t)d * H + lane];
            float csv = Cs[(size_t)d * H + lane];
            const int* sl = slots + d * CAPA;
            for (int j = wv; j < n; j += 16) {
                int idx[4]; float msk[4];
                #pragma unroll
                for (int v = 0; v < 4; ++v) {
                    int jc = j + 4 * v;
                    msk[v] = (jc < n) ? 1.0f : 0.0f;
                    idx[v] = sl[min(jc, n - 1)];
                }
                #pragma unroll
                for (int v = 0; v < 4; ++v) {
                    float2 a = __half22float2(gA[(size_t)idx[v] * H + lane]);
                    acc += msk[v] * (sigmoidf_(cfv + a.x) * softplusf_(csv + a.y));
                }
            }
        }
        // bond: on-the-fly from x_bond with register composite weights
        {
            int n = min(cnt[NC + d], CAPB);
            float cfv = Cf[(size_t)(NC + d) * H + lane];
            float csv = Cs[(size_t)(NC + d) * H + lane];
            __half2 wc[8];
            #pragma unroll
            for (int k = 0; k < 8; ++k) wc[k] = WcB[k * 64 + lane];
            const int* sl = slots + SLOTB + d * CAPB;
            for (int j = wv; j < n; j += 16) {
                int idx[4]; float msk[4];
                #pragma unroll
                for (int v = 0; v < 4; ++v) {
                    int jc = j + 4 * v;
                    msk[v] = (jc < n) ? 1.0f : 0.0f;
                    idx[v] = sl[min(jc, n - 1)];
                }
                float xr[4][7];
                #pragma unroll
                for (int v = 0; v < 4; ++v) {
                    const float* p = xb + (size_t)idx[v] * 7;
                    #pragma unroll
                    for (int k = 0; k < 7; ++k) xr[v][k] = p[k];
                }
                #pragma unroll
                for (int v = 0; v < 4; ++v) {
                    float gf = __low2float(wc[7]), gs = __high2float(wc[7]);
                    #pragma unroll
                    for (int k = 0; k < 7; ++k) {
                        gf = fmaf(xr[v][k], __low2float(wc[k]), gf);
                        gs = fmaf(xr[v][k], __high2float(wc[k]), gs);
                    }
                    acc += msk[v] * (sigmoidf_(cfv + gf) * softplusf_(csv + gs));
                }
            }
        }
        // motif: gather gM
        {
            int n = min(cnt[2 * NC + d], CAPM);
            float cfv = Cf[(size_t)(2 * NC + d) * H + lane];
            float csv = Cs[(size_t)(2 * NC + d) * H + lane];
            const int* sl = slots + SLOTM + d * CAPM;
            for (int j = wv; j < n; j += 16) {
                int idx[4]; float msk[4];
                #pragma unroll
                for (int v = 0; v < 4; ++v) {
                    int jc = j + 4 * v;
                    msk[v] = (jc < n) ? 1.0f : 0.0f;
                    idx[v] = sl[min(jc, n - 1)];
                }
                #pragma unroll
                for (int v = 0; v < 4; ++v) {
                    float2 a = __half22float2(gM[(size_t)idx[v] * H + lane]);
                    acc += msk[v] * (sigmoidf_(cfv + a.x) * softplusf_(csv + a.y));
                }
            }
        }

        red[wv * 64 + lane] = acc;
        __syncthreads();
        if (wv == 0) {
            float a = 3.0f * xc[(size_t)d * H + lane]
                    + red[lane] + red[64 + lane] + red[128 + lane] + red[192 + lane];
            vL[lane] = fmaxf(a, 0.0f);
            __builtin_amdgcn_s_waitcnt(0);    // wave-local LDS drain
            float aj = bp[lane];
            #pragma unroll
            for (int k = 0; k < H; ++k) aj = fmaf(vL[k], Wp[k * H + lane], aj);
            float contrib = softplusf_(aj) * Wo[lane];
            #pragma unroll
            for (int o = 32; o > 0; o >>= 1) contrib += __shfl_down(contrib, o, 64);
            if (lane == 0) out[d] = contrib + bo[0];
        }
        __syncthreads();                      // protect red/vL before next cell
    }
}

extern "C" void kernel_launch(void* const* d_in, const int* in_sizes, int n_in,
                              void* d_out, int out_size, void* d_ws, size_t ws_size,
                              hipStream_t stream)
{
    const float* xa = (const float*)d_in[0];
    const float* xb = (const float*)d_in[1];
    const float* xm = (const float*)d_in[2];
    const float* xc = (const float*)d_in[3];
    const float* Wa = (const float*)d_in[4];
    const float* ba = (const float*)d_in[5];
    const float* Wb = (const float*)d_in[6];
    const float* bb_ = (const float*)d_in[7];
    const float* Wm = (const float*)d_in[8];
    const float* bm = (const float*)d_in[9];
    const float* Wf = (const float*)d_in[10];
    const float* bf = (const float*)d_in[11];
    const float* Ws = (const float*)d_in[12];
    const float* bs = (const float*)d_in[13];
    const float* Wp = (const float*)d_in[14];
    const float* bp = (const float*)d_in[15];
    const float* Wo = (const float*)d_in[16];
    const float* bo = (const float*)d_in[17];
    const int* ea = (const int*)d_in[24];
    const int* eb = (const int*)d_in[25];
    const int* em = (const int*)d_in[26];

    // ---- workspace layout (256B-aligned), ~28 MB ----
    char* base = (char*)d_ws;
    size_t o = 0;
    auto alloc = [&](size_t bytes) { char* r = base + o; o = (o + bytes + 255) & ~(size_t)255; return r; };
    float*   Cf    = (float*)  alloc(3 * NC * H * sizeof(float));
    float*   Cs    = (float*)  alloc(3 * NC * H * sizeof(float));
    int*     cnt   = (int*)    alloc(3 * NC * sizeof(int));
    int*     slots = (int*)    alloc(SLOT_TOT * sizeof(int));
    short*   wpA   = (short*)  alloc(8 * 3 * 64 * 8 * sizeof(short));
    short*   wpM   = (short*)  alloc(8 * 2 * 64 * 8 * sizeof(short));
    float*   biasA = (float*)  alloc(128 * sizeof(float));
    float*   biasM = (float*)  alloc(128 * sizeof(float));
    __half2* WcB   = (__half2*)alloc(8 * 64 * sizeof(__half2));
    __half2* gA    = (__half2*)alloc((size_t)NA * H * sizeof(__half2));
    __half2* gM    = (__half2*)alloc((size_t)NM * H * sizeof(__half2));
    float*   out   = (float*)d_out;

    int blocksPerCU = 0;
    hipOccupancyMaxActiveBlocksPerMultiprocessor(&blocksPerCU, fused_kernel, 256, 0);
    if (blocksPerCU < 1) blocksPerCU = 1;
    int grid = blocksPerCU * 256;
    if (grid > 1024) grid = 1024;

    void* args[] = {
        (void*)&xa, (void*)&xb, (void*)&xm, (void*)&xc,
        (void*)&Wa, (void*)&ba, (void*)&Wb, (void*)&bb_,
        (void*)&Wm, (void*)&bm, (void*)&Wf, (void*)&bf,
        (void*)&Ws, (void*)&bs, (void*)&Wp, (void*)&bp,
        (void*)&Wo, (void*)&bo, (void*)&ea, (void*)&eb, (void*)&em,
        (void*)&Cf, (void*)&Cs, (void*)&cnt, (void*)&slots,
        (void*)&wpA, (void*)&wpM, (void*)&biasA, (void*)&biasM,
        (void*)&WcB, (void*)&gA, (void*)&gM, (void*)&out
    };
    hipLaunchCooperativeKernel(fused_kernel, dim3(grid), dim3(256), args, 0, stream);
}

// Round 10
// 90.918 us; speedup vs baseline: 2.5833x; 2.5833x over previous
//
#include <hip/hip_runtime.h>
#include <hip/hip_fp16.h>

#define H 64
#define NA 65536
#define NB 131072
#define NM 16384
#define NC 2048
#define E_AC 65536
#define E_BC 131072
#define E_MC 16384
#define NE_TOT (E_AC + E_BC + E_MC)

#define CAPA 160
#define CAPB 224
#define CAPM 96
#define SLOTB (NC * CAPA)
#define SLOTM (SLOTB + NC * CAPB)
#define SLOT_TOT (SLOTM + NC * CAPM)

typedef __attribute__((ext_vector_type(8))) short bf16x8;
typedef __attribute__((ext_vector_type(4))) float f32x4;

__device__ __forceinline__ float sigmoidf_(float x) { return 1.0f / (1.0f + __expf(-x)); }
__device__ __forceinline__ float softplusf_(float x) {
    return fmaxf(x, 0.0f) + __logf(1.0f + __expf(-fabsf(x)));
}
__device__ __forceinline__ short bf16_of(float f) {
    union { float f; unsigned u; } v; v.f = f;
    unsigned r = (v.u + 0x7fff + ((v.u >> 16) & 1)) >> 16;  // RNE
    return (short)r;
}

// ================= K0: prep0 — zero cnt + weight packs (85 blocks) =================
// [0,48): atom MFMA-pack  [48,80): motif MFMA-pack  80: biasA  81: biasM  [82,84): WcB
__global__ __launch_bounds__(256) void prep0_kernel(
    const float* __restrict__ Wa, const float* __restrict__ ba,
    const float* __restrict__ Wb, const float* __restrict__ bb_,
    const float* __restrict__ Wm, const float* __restrict__ bm,
    const float* __restrict__ Wf, const float* __restrict__ Ws,
    short* __restrict__ wpA, short* __restrict__ wpM,
    float* __restrict__ biasA, float* __restrict__ biasM,
    __half2* __restrict__ WcB, int* __restrict__ cnt)
{
    int b = blockIdx.x, tid = threadIdx.x;
    for (int i = b * 256 + tid; i < 3 * NC; i += gridDim.x * 256) cnt[i] = 0;

    if (b < 48) {                             // atom MFMA-pack: 96x128
        int idx = b * 256 + tid;
        int k = idx >> 7, col = idx & 127, c = col & 63;
        const float* WB = ((col < 64) ? Wf : Ws) + (size_t)6 * 2 * H * H + (size_t)H * H;
        float v = 0.0f;
        if (k < 92) {
            const float* a = Wa + (size_t)k * H;
            for (int j = 0; j < H; ++j) v = fmaf(a[j], WB[j * H + c], v);
        }
        int t = col >> 4, lo = col & 15, sm = k >> 5, q = (k >> 3) & 3, e = k & 7;
        wpA[(size_t)(((t * 3 + sm) * 64) + q * 16 + lo) * 8 + e] = bf16_of(v);
    } else if (b < 80) {                      // motif MFMA-pack: 64x128
        int idx = (b - 48) * 256 + tid;
        int k = idx >> 7, col = idx & 127, c = col & 63;
        const float* WB = ((col < 64) ? Wf : Ws) + (size_t)8 * 2 * H * H + (size_t)H * H;
        float v = 0.0f;
        if (k < 35) {
            const float* a = Wm + (size_t)k * H;
            for (int j = 0; j < H; ++j) v = fmaf(a[j], WB[j * H + c], v);
        }
        int t = col >> 4, lo = col & 15, sm = k >> 5, q = (k >> 3) & 3, e = k & 7;
        wpM[(size_t)(((t * 2 + sm) * 64) + q * 16 + lo) * 8 + e] = bf16_of(v);
    } else if (b == 80) {
        if (tid < 128) {
            int col = tid, c = col & 63;
            const float* WB = ((col < 64) ? Wf : Ws) + (size_t)6 * 2 * H * H + (size_t)H * H;
            float v = 0.0f;
            for (int j = 0; j < H; ++j) v = fmaf(ba[j], WB[j * H + c], v);
            biasA[col] = v;
        }
    } else if (b == 81) {
        if (tid < 128) {
            int col = tid, c = col & 63;
            const float* WB = ((col < 64) ? Wf : Ws) + (size_t)8 * 2 * H * H + (size_t)H * H;
            float v = 0.0f;
            for (int j = 0; j < H; ++j) v = fmaf(bm[j], WB[j * H + c], v);
            biasM[col] = v;
        }
    } else if (b < 84) {
        int idx = (b - 82) * 256 + tid;
        if (idx < 8 * 64) {
            int k = idx >> 6, col = idx & 63;
            const float* WfB = Wf + (size_t)7 * 2 * H * H + (size_t)H * H;
            const float* WsB = Ws + (size_t)7 * 2 * H * H + (size_t)H * H;
            const float* row = (k < 7) ? (Wb + (size_t)k * H) : bb_;
            float f = 0.0f, s = 0.0f;
            for (int j = 0; j < H; ++j) {
                float rv = row[j];
                f = fmaf(rv, WfB[j * H + col], f);
                s = fmaf(rv, WsB[j * H + col], s);
            }
            WcB[k * 64 + col] = __floats2half2_rn(f, s);
        }
    }
    // block 84: cnt-zero only
}

// ---------------- G build tile: one wave = 16 rows x 128 cols ----------------
template<int K, int S, bool VEC>
__device__ __forceinline__ void gmfma_body(
    int blk, const float* __restrict__ x, const short* __restrict__ wp,
    const float* __restrict__ bias, __half2* __restrict__ g)
{
    int l = threadIdx.x & 63;
    int wv = threadIdx.x >> 6;
    int r0 = (blk * 4 + wv) * 16;
    int lrow = l & 15, q = l >> 4;

    float bF[4], bS[4];
    #pragma unroll
    for (int t = 0; t < 4; ++t) {
        bF[t] = bias[t * 16 + lrow];
        bS[t] = bias[64 + t * 16 + lrow];
    }

    f32x4 acc[8];
    #pragma unroll
    for (int t = 0; t < 8; ++t) acc[t] = (f32x4){0.f, 0.f, 0.f, 0.f};

    const float* xr = x + (size_t)(r0 + lrow) * K;
    #pragma unroll
    for (int s = 0; s < S; ++s) {
        int kb = s * 32 + q * 8;
        bf16x8 afrag;
        if (VEC && kb + 8 <= K) {                 // K=92: row stride 368B, 16B-aligned
            float4 v0 = *(const float4*)(xr + kb);
            float4 v1 = *(const float4*)(xr + kb + 4);
            afrag[0] = bf16_of(v0.x); afrag[1] = bf16_of(v0.y);
            afrag[2] = bf16_of(v0.z); afrag[3] = bf16_of(v0.w);
            afrag[4] = bf16_of(v1.x); afrag[5] = bf16_of(v1.y);
            afrag[6] = bf16_of(v1.z); afrag[7] = bf16_of(v1.w);
        } else {
            #pragma unroll
            for (int e = 0; e < 8; ++e) {
                float xv = 0.0f;
                if (kb + e < K) xv = xr[kb + e];
                afrag[e] = bf16_of(xv);
            }
        }
        #pragma unroll
        for (int t = 0; t < 8; ++t) {
            bf16x8 bt = *(const bf16x8*)(wp + (size_t)((t * S + s) * 64 + l) * 8);
            acc[t] = __builtin_amdgcn_mfma_f32_16x16x32_bf16(afrag, bt, acc[t], 0, 0, 0);
        }
    }

    #pragma unroll
    for (int t = 0; t < 4; ++t)
        #pragma unroll
        for (int r = 0; r < 4; ++r) {
            float fv = acc[t][r] + bF[t];
            float sv = acc[t + 4][r] + bS[t];
            g[(size_t)(r0 + q * 4 + r) * H + t * 16 + lrow] = __floats2half2_rn(fv, sv);
        }
}

// ================= K1: work — G build + cellpart + edge append (1768 blocks) =========
// [0,1024): atom G  [1024,1280): motif G  [1280,1664): cellpart  [1664,1768): append
__global__ __launch_bounds__(256) void work_kernel(
    const float* __restrict__ xa, const float* __restrict__ xm, const float* __restrict__ xc,
    const float* __restrict__ Wf, const float* __restrict__ bf,
    const float* __restrict__ Ws, const float* __restrict__ bs,
    const short* __restrict__ wpA, const float* __restrict__ biasA,
    const short* __restrict__ wpM, const float* __restrict__ biasM,
    const int* __restrict__ ea, const int* __restrict__ eb, const int* __restrict__ em,
    float* __restrict__ Cf, float* __restrict__ Cs,
    int* __restrict__ cnt, int* __restrict__ slots,
    __half2* __restrict__ gA, __half2* __restrict__ gM)
{
    __shared__ float Wl[2][H * H];               // used by cellpart branch only (32 KB)
    int b = blockIdx.x, tid = threadIdx.x;
    if (b < 1024) {
        gmfma_body<92, 3, true>(b, xa, wpA, biasA, gA);
    } else if (b < 1280) {
        gmfma_body<35, 2, false>(b - 1024, xm, wpM, biasM, gM);
    } else if (b < 1664) {                       // cellpart
        int cu = b - 1280;                       // 0..383
        int r = cu / 128, rowblk = cu % 128;
        const float* WfT = Wf + (size_t)(6 + r) * 2 * H * H;
        const float* WsT = Ws + (size_t)(6 + r) * 2 * H * H;
        for (int i = tid; i < H * H; i += 256) { Wl[0][i] = WfT[i]; Wl[1][i] = WsT[i]; }
        __syncthreads();
        int col = tid & 63, rgrp = tid >> 6;
        float bfv = bf[(6 + r) * H + col], bsv = bs[(6 + r) * H + col];
        #pragma unroll
        for (int rr = 0; rr < 4; ++rr) {
            int row = rowblk * 16 + rgrp * 4 + rr;
            const float* xr = xc + (size_t)row * H;
            float af = bfv, as = bsv;
            #pragma unroll
            for (int k = 0; k < H; ++k) {
                float xv = xr[k];
                af = fmaf(xv, Wl[0][k * H + col], af);
                as = fmaf(xv, Wl[1][k * H + col], as);
            }
            Cf[((size_t)r * NC + row) * H + col] = af;
            Cs[((size_t)r * NC + row) * H + col] = as;
        }
    } else {                                     // edge append
        int t0 = (b - 1664) * 256 + tid;         // 0..26623
        #pragma unroll
        for (int u2 = 0; u2 < 8; ++u2) {
            int i = t0 + u2 * 26624;
            int r, d, s;
            if (i < E_AC)             { r = 0; s = ea[i];                 d = ea[E_AC + i]; }
            else if (i < E_AC + E_BC) { int k = i - E_AC; r = 1; s = eb[k]; d = eb[E_BC + k]; }
            else                      { int k = i - E_AC - E_BC; r = 2; s = em[k]; d = em[E_MC + k]; }
            int pos = atomicAdd(&cnt[r * NC + d], 1);
            int base, cap;
            if (r == 0)      { base = d * CAPA;         cap = CAPA; }
            else if (r == 1) { base = SLOTB + d * CAPB; cap = CAPB; }
            else             { base = SLOTM + d * CAPM; cap = CAPM; }
            if (pos < cap) slots[base + pos] = s;
        }
    }
}

// ================= K2: per-cell accumulate + head (2048 blocks x 512) =================
__global__ __launch_bounds__(512) void cellacc_kernel(
    const __half2* __restrict__ gA, const __half2* __restrict__ gM,
    const float* __restrict__ xb, const __half2* __restrict__ WcB,
    const int* __restrict__ slots, const int* __restrict__ cnt,
    const float* __restrict__ Cf, const float* __restrict__ Cs,
    const float* __restrict__ xc,
    const float* __restrict__ Wp, const float* __restrict__ bp,
    const float* __restrict__ Wo, const float* __restrict__ bo,
    float* __restrict__ out)
{
    __shared__ float red[8][H];
    __shared__ float vL[H];
    int d = blockIdx.x;
    int lane = threadIdx.x & 63, wv = threadIdx.x >> 6;   // 8 waves
    float acc = 0.0f;

    // atom: gather gA
    {
        int n = min(cnt[d], CAPA);
        float cfv = Cf[(size_t)d * H + lane];
        float csv = Cs[(size_t)d * H + lane];
        const int* sl = slots + d * CAPA;
        for (int j = wv; j < n; j += 32) {
            int idx[4]; float msk[4];
            #pragma unroll
            for (int v = 0; v < 4; ++v) {
                int jc = j + 8 * v;
                msk[v] = (jc < n) ? 1.0f : 0.0f;
                idx[v] = sl[min(jc, n - 1)];
            }
            #pragma unroll
            for (int v = 0; v < 4; ++v) {
                float2 a = __half22float2(gA[(size_t)idx[v] * H + lane]);
                acc += msk[v] * (sigmoidf_(cfv + a.x) * softplusf_(csv + a.y));
            }
        }
    }
    // bond: on-the-fly from x_bond with register composite weights
    {
        int n = min(cnt[NC + d], CAPB);
        float cfv = Cf[(size_t)(NC + d) * H + lane];
        float csv = Cs[(size_t)(NC + d) * H + lane];
        __half2 wc[8];
        #pragma unroll
        for (int k = 0; k < 8; ++k) wc[k] = WcB[k * 64 + lane];
        const int* sl = slots + SLOTB + d * CAPB;
        for (int j = wv; j < n; j += 32) {
            int idx[4]; float msk[4];
            #pragma unroll
            for (int v = 0; v < 4; ++v) {
                int jc = j + 8 * v;
                msk[v] = (jc < n) ? 1.0f : 0.0f;
                idx[v] = sl[min(jc, n - 1)];
            }
            float xr[4][7];
            #pragma unroll
            for (int v = 0; v < 4; ++v) {
                const float* p = xb + (size_t)idx[v] * 7;
                #pragma unroll
                for (int k = 0; k < 7; ++k) xr[v][k] = p[k];
            }
            #pragma unroll
            for (int v = 0; v < 4; ++v) {
                float gf = __low2float(wc[7]), gs = __high2float(wc[7]);
                #pragma unroll
                for (int k = 0; k < 7; ++k) {
                    gf = fmaf(xr[v][k], __low2float(wc[k]), gf);
                    gs = fmaf(xr[v][k], __high2float(wc[k]), gs);
                }
                acc += msk[v] * (sigmoidf_(cfv + gf) * softplusf_(csv + gs));
            }
        }
    }
    // motif: gather gM
    {
        int n = min(cnt[2 * NC + d], CAPM);
        float cfv = Cf[(size_t)(2 * NC + d) * H + lane];
        float csv = Cs[(size_t)(2 * NC + d) * H + lane];
        const int* sl = slots + SLOTM + d * CAPM;
        for (int j = wv; j < n; j += 32) {
            int idx[4]; float msk[4];
            #pragma unroll
            for (int v = 0; v < 4; ++v) {
                int jc = j + 8 * v;
                msk[v] = (jc < n) ? 1.0f : 0.0f;
                idx[v] = sl[min(jc, n - 1)];
            }
            #pragma unroll
            for (int v = 0; v < 4; ++v) {
                float2 a = __half22float2(gM[(size_t)idx[v] * H + lane]);
                acc += msk[v] * (sigmoidf_(cfv + a.x) * softplusf_(csv + a.y));
            }
        }
    }

    red[wv][lane] = acc;
    __syncthreads();
    if (wv == 0) {
        float a = 3.0f * xc[(size_t)d * H + lane];
        #pragma unroll
        for (int w = 0; w < 8; ++w) a += red[w][lane];
        vL[lane] = fmaxf(a, 0.0f);
        __builtin_amdgcn_s_waitcnt(0);   // wave-local LDS drain
        float aj = bp[lane];
        #pragma unroll
        for (int k = 0; k < H; ++k) aj = fmaf(vL[k], Wp[k * H + lane], aj);
        float contrib = softplusf_(aj) * Wo[lane];
        #pragma unroll
        for (int o = 32; o > 0; o >>= 1) contrib += __shfl_down(contrib, o, 64);
        if (lane == 0) out[d] = contrib + bo[0];
    }
}

extern "C" void kernel_launch(void* const* d_in, const int* in_sizes, int n_in,
                              void* d_out, int out_size, void* d_ws, size_t ws_size,
                              hipStream_t stream)
{
    const float* xa = (const float*)d_in[0];
    const float* xb = (const float*)d_in[1];
    const float* xm = (const float*)d_in[2];
    const float* xc = (const float*)d_in[3];
    const float* Wa = (const float*)d_in[4];
    const float* ba = (const float*)d_in[5];
    const float* Wb = (const float*)d_in[6];
    const float* bb_ = (const float*)d_in[7];
    const float* Wm = (const float*)d_in[8];
    const float* bm = (const float*)d_in[9];
    const float* Wf = (const float*)d_in[10];
    const float* bf = (const float*)d_in[11];
    const float* Ws = (const float*)d_in[12];
    const float* bs = (const float*)d_in[13];
    const float* Wp = (const float*)d_in[14];
    const float* bp = (const float*)d_in[15];
    const float* Wo = (const float*)d_in[16];
    const float* bo = (const float*)d_in[17];
    const int* ea = (const int*)d_in[24];
    const int* eb = (const int*)d_in[25];
    const int* em = (const int*)d_in[26];

    // ---- workspace layout (256B-aligned), ~28 MB ----
    char* base = (char*)d_ws;
    size_t o = 0;
    auto alloc = [&](size_t bytes) { char* r = base + o; o = (o + bytes + 255) & ~(size_t)255; return r; };
    float*   Cf    = (float*)  alloc(3 * NC * H * sizeof(float));
    float*   Cs    = (float*)  alloc(3 * NC * H * sizeof(float));
    int*     cnt   = (int*)    alloc(3 * NC * sizeof(int));
    int*     slots = (int*)    alloc(SLOT_TOT * sizeof(int));
    short*   wpA   = (short*)  alloc(8 * 3 * 64 * 8 * sizeof(short));
    short*   wpM   = (short*)  alloc(8 * 2 * 64 * 8 * sizeof(short));
    float*   biasA = (float*)  alloc(128 * sizeof(float));
    float*   biasM = (float*)  alloc(128 * sizeof(float));
    __half2* WcB   = (__half2*)alloc(8 * 64 * sizeof(__half2));
    __half2* gA    = (__half2*)alloc((size_t)NA * H * sizeof(__half2));
    __half2* gM    = (__half2*)alloc((size_t)NM * H * sizeof(__half2));
    float*   out   = (float*)d_out;

    prep0_kernel<<<85, 256, 0, stream>>>(Wa, ba, Wb, bb_, Wm, bm, Wf, Ws,
                                         wpA, wpM, biasA, biasM, WcB, cnt);
    work_kernel<<<1768, 256, 0, stream>>>(xa, xm, xc, Wf, bf, Ws, bs,
                                          wpA, biasA, wpM, biasM,
                                          ea, eb, em, Cf, Cs, cnt, slots, gA, gM);
    cellacc_kernel<<<NC, 512, 0, stream>>>(gA, gM, xb, WcB, slots, cnt, Cf, Cs,
                                           xc, Wp, bp, Wo, bo, out);
}

// Round 11
// 77.324 us; speedup vs baseline: 3.0375x; 1.1758x over previous
//
#include <hip/hip_runtime.h>
#include <hip/hip_fp16.h>

#define H 64
#define NA 65536
#define NB 131072
#define NM 16384
#define NC 2048
#define E_AC 65536
#define E_BC 131072
#define E_MC 16384
#define NE_TOT (E_AC + E_BC + E_MC)

#define CAPA 160
#define CAPB 224
#define CAPM 96
#define SLOTB (NC * CAPA)
#define SLOTM (SLOTB + NC * CAPB)
#define SLOT_TOT (SLOTM + NC * CAPM)

typedef __attribute__((ext_vector_type(8))) short bf16x8;
typedef __attribute__((ext_vector_type(4))) float f32x4;

__device__ __forceinline__ float sigmoidf_(float x) { return 1.0f / (1.0f + __expf(-x)); }
__device__ __forceinline__ float softplusf_(float x) {
    return fmaxf(x, 0.0f) + __logf(1.0f + __expf(-fabsf(x)));
}
__device__ __forceinline__ short bf16_of(float f) {
    union { float f; unsigned u; } v; v.f = f;
    unsigned r = (v.u + 0x7fff + ((v.u >> 16) & 1)) >> 16;  // RNE
    return (short)r;
}

// ================= K0: prep0 — zero cnt + weight packs (181 blocks) =================
// [0,48): atom pack  [48,80): motif pack  [80,176): cell pack (3 rel x 32)
// 176: biasA  177: biasM  178: biasC  [179,181): WcB
__global__ __launch_bounds__(256) void prep0_kernel(
    const float* __restrict__ Wa, const float* __restrict__ ba,
    const float* __restrict__ Wb, const float* __restrict__ bb_,
    const float* __restrict__ Wm, const float* __restrict__ bm,
    const float* __restrict__ Wf, const float* __restrict__ bf,
    const float* __restrict__ Ws, const float* __restrict__ bs,
    short* __restrict__ wpA, short* __restrict__ wpM, short* __restrict__ wpC,
    float* __restrict__ biasA, float* __restrict__ biasM, float* __restrict__ biasC,
    __half2* __restrict__ WcB, int* __restrict__ cnt)
{
    int b = blockIdx.x, tid = threadIdx.x;
    for (int i = b * 256 + tid; i < 3 * NC; i += gridDim.x * 256) cnt[i] = 0;

    if (b < 48) {                             // atom composite pack: 96x128, S=3
        int idx = b * 256 + tid;
        int k = idx >> 7, col = idx & 127, c = col & 63;
        const float* WB = ((col < 64) ? Wf : Ws) + (size_t)6 * 2 * H * H + (size_t)H * H;
        float v = 0.0f;
        if (k < 92) {
            const float* a = Wa + (size_t)k * H;
            for (int j = 0; j < H; ++j) v = fmaf(a[j], WB[j * H + c], v);
        }
        int t = col >> 4, lo = col & 15, sm = k >> 5, q = (k >> 3) & 3, e = k & 7;
        wpA[(size_t)(((t * 3 + sm) * 64) + q * 16 + lo) * 8 + e] = bf16_of(v);
    } else if (b < 80) {                      // motif composite pack: 64x128, S=2
        int idx = (b - 48) * 256 + tid;
        int k = idx >> 7, col = idx & 127, c = col & 63;
        const float* WB = ((col < 64) ? Wf : Ws) + (size_t)8 * 2 * H * H + (size_t)H * H;
        float v = 0.0f;
        if (k < 35) {
            const float* a = Wm + (size_t)k * H;
            for (int j = 0; j < H; ++j) v = fmaf(a[j], WB[j * H + c], v);
        }
        int t = col >> 4, lo = col & 15, sm = k >> 5, q = (k >> 3) & 3, e = k & 7;
        wpM[(size_t)(((t * 2 + sm) * 64) + q * 16 + lo) * 8 + e] = bf16_of(v);
    } else if (b < 176) {                     // cell top-half relayout: 3 x 64x128, S=2
        int cu = b - 80;
        int rel = cu >> 5;                    // /32
        int idx = (cu & 31) * 256 + tid;
        int k = idx >> 7, col = idx & 127, c = col & 63;
        float v = ((col < 64) ? Wf : Ws)[(size_t)(6 + rel) * 2 * H * H + (size_t)k * H + c];
        int t = col >> 4, lo = col & 15, sm = k >> 5, q = (k >> 3) & 3, e = k & 7;
        wpC[(size_t)rel * 8192 + (size_t)(((t * 2 + sm) * 64) + q * 16 + lo) * 8 + e] = bf16_of(v);
    } else if (b == 176) {
        if (tid < 128) {
            int col = tid, c = col & 63;
            const float* WB = ((col < 64) ? Wf : Ws) + (size_t)6 * 2 * H * H + (size_t)H * H;
            float v = 0.0f;
            for (int j = 0; j < H; ++j) v = fmaf(ba[j], WB[j * H + c], v);
            biasA[col] = v;
        }
    } else if (b == 177) {
        if (tid < 128) {
            int col = tid, c = col & 63;
            const float* WB = ((col < 64) ? Wf : Ws) + (size_t)8 * 2 * H * H + (size_t)H * H;
            float v = 0.0f;
            for (int j = 0; j < H; ++j) v = fmaf(bm[j], WB[j * H + c], v);
            biasM[col] = v;
        }
    } else if (b == 178) {
        for (int i = tid; i < 384; i += 256) {
            int rel = i >> 7, col = i & 127, c = col & 63;
            biasC[rel * 128 + col] = ((col < 64) ? bf : bs)[(6 + rel) * H + c];
        }
    } else if (b < 181) {
        int idx = (b - 179) * 256 + tid;
        if (idx < 8 * 64) {
            int k = idx >> 6, col = idx & 63;
            const float* WfB = Wf + (size_t)7 * 2 * H * H + (size_t)H * H;
            const float* WsB = Ws + (size_t)7 * 2 * H * H + (size_t)H * H;
            const float* row = (k < 7) ? (Wb + (size_t)k * H) : bb_;
            float f = 0.0f, s = 0.0f;
            for (int j = 0; j < H; ++j) {
                float rv = row[j];
                f = fmaf(rv, WfB[j * H + col], f);
                s = fmaf(rv, WsB[j * H + col], s);
            }
            WcB[k * 64 + col] = __floats2half2_rn(f, s);
        }
    }
}

// ---------------- G build tile: one wave = 16 rows x 128 cols, no LDS ----------------
template<int K, int S, bool VEC>
__device__ __forceinline__ void gmfma_body(
    int blk, const float* __restrict__ x, const short* __restrict__ wp,
    const float* __restrict__ bias, __half2* __restrict__ g)
{
    int l = threadIdx.x & 63;
    int wv = threadIdx.x >> 6;
    int r0 = (blk * 4 + wv) * 16;
    int lrow = l & 15, q = l >> 4;

    float bF[4], bS[4];
    #pragma unroll
    for (int t = 0; t < 4; ++t) {
        bF[t] = bias[t * 16 + lrow];
        bS[t] = bias[64 + t * 16 + lrow];
    }

    f32x4 acc[8];
    #pragma unroll
    for (int t = 0; t < 8; ++t) acc[t] = (f32x4){0.f, 0.f, 0.f, 0.f};

    const float* xr = x + (size_t)(r0 + lrow) * K;
    #pragma unroll
    for (int s = 0; s < S; ++s) {
        int kb = s * 32 + q * 8;
        bf16x8 afrag;
        if (VEC && kb + 8 <= K) {
            float4 v0 = *(const float4*)(xr + kb);
            float4 v1 = *(const float4*)(xr + kb + 4);
            afrag[0] = bf16_of(v0.x); afrag[1] = bf16_of(v0.y);
            afrag[2] = bf16_of(v0.z); afrag[3] = bf16_of(v0.w);
            afrag[4] = bf16_of(v1.x); afrag[5] = bf16_of(v1.y);
            afrag[6] = bf16_of(v1.z); afrag[7] = bf16_of(v1.w);
        } else {
            #pragma unroll
            for (int e = 0; e < 8; ++e) {
                float xv = 0.0f;
                if (kb + e < K) xv = xr[kb + e];
                afrag[e] = bf16_of(xv);
            }
        }
        #pragma unroll
        for (int t = 0; t < 8; ++t) {
            bf16x8 bt = *(const bf16x8*)(wp + (size_t)((t * S + s) * 64 + l) * 8);
            acc[t] = __builtin_amdgcn_mfma_f32_16x16x32_bf16(afrag, bt, acc[t], 0, 0, 0);
        }
    }

    #pragma unroll
    for (int t = 0; t < 4; ++t)
        #pragma unroll
        for (int r = 0; r < 4; ++r) {
            float fv = acc[t][r] + bF[t];
            float sv = acc[t + 4][r] + bS[t];
            g[(size_t)(r0 + q * 4 + r) * H + t * 16 + lrow] = __floats2half2_rn(fv, sv);
        }
}

// ================= K1: work (1480 blocks, append FIRST, no LDS) =================
// [0,104): edge append  [104,200): cell C (3x32)  [200,456): motif G  [456,1480): atom G
__global__ __launch_bounds__(256) void work_kernel(
    const float* __restrict__ xa, const float* __restrict__ xm, const float* __restrict__ xc,
    const short* __restrict__ wpA, const float* __restrict__ biasA,
    const short* __restrict__ wpM, const float* __restrict__ biasM,
    const short* __restrict__ wpC, const float* __restrict__ biasC,
    const int* __restrict__ ea, const int* __restrict__ eb, const int* __restrict__ em,
    int* __restrict__ cnt, int* __restrict__ slots,
    __half2* __restrict__ gA, __half2* __restrict__ gM, __half2* __restrict__ Ccomb)
{
    int b = blockIdx.x, tid = threadIdx.x;
    if (b < 104) {                               // edge append (contended atomics start early)
        int t0 = b * 256 + tid;                  // 0..26623
        #pragma unroll
        for (int u2 = 0; u2 < 8; ++u2) {
            int i = t0 + u2 * 26624;
            int r, d, s;
            if (i < E_AC)             { r = 0; s = ea[i];                 d = ea[E_AC + i]; }
            else if (i < E_AC + E_BC) { int k = i - E_AC; r = 1; s = eb[k]; d = eb[E_BC + k]; }
            else                      { int k = i - E_AC - E_BC; r = 2; s = em[k]; d = em[E_MC + k]; }
            int pos = atomicAdd(&cnt[r * NC + d], 1);
            int base, cap;
            if (r == 0)      { base = d * CAPA;         cap = CAPA; }
            else if (r == 1) { base = SLOTB + d * CAPB; cap = CAPB; }
            else             { base = SLOTM + d * CAPM; cap = CAPM; }
            if (pos < cap) slots[base + pos] = s;
        }
    } else if (b < 200) {                        // cell C build via MFMA relayout
        int cu = b - 104;
        int rel = cu >> 5, blk = cu & 31;
        gmfma_body<64, 2, true>(blk, xc, wpC + (size_t)rel * 8192, biasC + rel * 128,
                                Ccomb + (size_t)rel * NC * H);
    } else if (b < 456) {
        gmfma_body<35, 2, false>(b - 200, xm, wpM, biasM, gM);
    } else {
        gmfma_body<92, 3, true>(b - 456, xa, wpA, biasA, gA);
    }
}

// ================= K2: per-cell accumulate + head (2048 blocks x 512) =================
__global__ __launch_bounds__(512) void cellacc_kernel(
    const __half2* __restrict__ gA, const __half2* __restrict__ gM,
    const float* __restrict__ xb, const __half2* __restrict__ WcB,
    const int* __restrict__ slots, const int* __restrict__ cnt,
    const __half2* __restrict__ Ccomb, const float* __restrict__ xc,
    const float* __restrict__ Wp, const float* __restrict__ bp,
    const float* __restrict__ Wo, const float* __restrict__ bo,
    float* __restrict__ out)
{
    __shared__ float red[8][H];
    __shared__ float vL[H];
    int d = blockIdx.x;
    int lane = threadIdx.x & 63, wv = threadIdx.x >> 6;   // 8 waves
    float acc = 0.0f;

    // atom: gather gA
    {
        int n = min(cnt[d], CAPA);
        float2 cc = __half22float2(Ccomb[(size_t)d * H + lane]);
        const int* sl = slots + d * CAPA;
        for (int j = wv; j < n; j += 32) {
            int idx[4]; float msk[4];
            #pragma unroll
            for (int v = 0; v < 4; ++v) {
                int jc = j + 8 * v;
                msk[v] = (jc < n) ? 1.0f : 0.0f;
                idx[v] = sl[min(jc, n - 1)];
            }
            #pragma unroll
            for (int v = 0; v < 4; ++v) {
                float2 a = __half22float2(gA[(size_t)idx[v] * H + lane]);
                acc += msk[v] * (sigmoidf_(cc.x + a.x) * softplusf_(cc.y + a.y));
            }
        }
    }
    // bond: on-the-fly from x_bond with register composite weights
    {
        int n = min(cnt[NC + d], CAPB);
        float2 cc = __half22float2(Ccomb[(size_t)(NC + d) * H + lane]);
        __half2 wc[8];
        #pragma unroll
        for (int k = 0; k < 8; ++k) wc[k] = WcB[k * 64 + lane];
        const int* sl = slots + SLOTB + d * CAPB;
        for (int j = wv; j < n; j += 32) {
            int idx[4]; float msk[4];
            #pragma unroll
            for (int v = 0; v < 4; ++v) {
                int jc = j + 8 * v;
                msk[v] = (jc < n) ? 1.0f : 0.0f;
                idx[v] = sl[min(jc, n - 1)];
            }
            float xr[4][7];
            #pragma unroll
            for (int v = 0; v < 4; ++v) {
                const float* p = xb + (size_t)idx[v] * 7;
                #pragma unroll
                for (int k = 0; k < 7; ++k) xr[v][k] = p[k];
            }
            #pragma unroll
            for (int v = 0; v < 4; ++v) {
                float gf = __low2float(wc[7]), gs = __high2float(wc[7]);
                #pragma unroll
                for (int k = 0; k < 7; ++k) {
                    gf = fmaf(xr[v][k], __low2float(wc[k]), gf);
                    gs = fmaf(xr[v][k], __high2float(wc[k]), gs);
                }
                acc += msk[v] * (sigmoidf_(cc.x + gf) * softplusf_(cc.y + gs));
            }
        }
    }
    // motif: gather gM
    {
        int n = min(cnt[2 * NC + d], CAPM);
        float2 cc = __half22float2(Ccomb[(size_t)(2 * NC + d) * H + lane]);
        const int* sl = slots + SLOTM + d * CAPM;
        for (int j = wv; j < n; j += 32) {
            int idx[4]; float msk[4];
            #pragma unroll
            for (int v = 0; v < 4; ++v) {
                int jc = j + 8 * v;
                msk[v] = (jc < n) ? 1.0f : 0.0f;
                idx[v] = sl[min(jc, n - 1)];
            }
            #pragma unroll
            for (int v = 0; v < 4; ++v) {
                float2 a = __half22float2(gM[(size_t)idx[v] * H + lane]);
                acc += msk[v] * (sigmoidf_(cc.x + a.x) * softplusf_(cc.y + a.y));
            }
        }
    }

    red[wv][lane] = acc;
    __syncthreads();
    if (wv == 0) {
        float a = 3.0f * xc[(size_t)d * H + lane];
        #pragma unroll
        for (int w = 0; w < 8; ++w) a += red[w][lane];
        vL[lane] = fmaxf(a, 0.0f);
        __builtin_amdgcn_s_waitcnt(0);   // wave-local LDS drain
        float aj = bp[lane];
        #pragma unroll
        for (int k = 0; k < H; ++k) aj = fmaf(vL[k], Wp[k * H + lane], aj);
        float contrib = softplusf_(aj) * Wo[lane];
        #pragma unroll
        for (int o = 32; o > 0; o >>= 1) contrib += __shfl_down(contrib, o, 64);
        if (lane == 0) out[d] = contrib + bo[0];
    }
}

extern "C" void kernel_launch(void* const* d_in, const int* in_sizes, int n_in,
                              void* d_out, int out_size, void* d_ws, size_t ws_size,
                              hipStream_t stream)
{
    const float* xa = (const float*)d_in[0];
    const float* xb = (const float*)d_in[1];
    const float* xm = (const float*)d_in[2];
    const float* xc = (const float*)d_in[3];
    const float* Wa = (const float*)d_in[4];
    const float* ba = (const float*)d_in[5];
    const float* Wb = (const float*)d_in[6];
    const float* bb_ = (const float*)d_in[7];
    const float* Wm = (const float*)d_in[8];
    const float* bm = (const float*)d_in[9];
    const float* Wf = (const float*)d_in[10];
    const float* bf = (const float*)d_in[11];
    const float* Ws = (const float*)d_in[12];
    const float* bs = (const float*)d_in[13];
    const float* Wp = (const float*)d_in[14];
    const float* bp = (const float*)d_in[15];
    const float* Wo = (const float*)d_in[16];
    const float* bo = (const float*)d_in[17];
    const int* ea = (const int*)d_in[24];
    const int* eb = (const int*)d_in[25];
    const int* em = (const int*)d_in[26];

    // ---- workspace layout (256B-aligned), ~27 MB ----
    char* base = (char*)d_ws;
    size_t o = 0;
    auto alloc = [&](size_t bytes) { char* r = base + o; o = (o + bytes + 255) & ~(size_t)255; return r; };
    int*     cnt   = (int*)    alloc(3 * NC * sizeof(int));
    int*     slots = (int*)    alloc(SLOT_TOT * sizeof(int));
    short*   wpA   = (short*)  alloc(8 * 3 * 64 * 8 * sizeof(short));
    short*   wpM   = (short*)  alloc(8 * 2 * 64 * 8 * sizeof(short));
    short*   wpC   = (short*)  alloc(3 * 8192 * sizeof(short));
    float*   biasA = (float*)  alloc(128 * sizeof(float));
    float*   biasM = (float*)  alloc(128 * sizeof(float));
    float*   biasC = (float*)  alloc(384 * sizeof(float));
    __half2* WcB   = (__half2*)alloc(8 * 64 * sizeof(__half2));
    __half2* Ccomb = (__half2*)alloc((size_t)3 * NC * H * sizeof(__half2));
    __half2* gA    = (__half2*)alloc((size_t)NA * H * sizeof(__half2));
    __half2* gM    = (__half2*)alloc((size_t)NM * H * sizeof(__half2));
    float*   out   = (float*)d_out;

    prep0_kernel<<<181, 256, 0, stream>>>(Wa, ba, Wb, bb_, Wm, bm, Wf, bf, Ws, bs,
                                          wpA, wpM, wpC, biasA, biasM, biasC, WcB, cnt);
    work_kernel<<<1480, 256, 0, stream>>>(xa, xm, xc, wpA, biasA, wpM, biasM, wpC, biasC,
                                          ea, eb, em, cnt, slots, gA, gM, Ccomb);
    cellacc_kernel<<<NC, 512, 0, stream>>>(gA, gM, xb, WcB, slots, cnt, Ccomb,
                                           xc, Wp, bp, Wo, bo, out);
}